// Round 8
// baseline (85.588 us; speedup 1.0000x reference)
//
#include <hip/hip_runtime.h>
#include <hip/hip_bf16.h>

typedef __bf16 bf16t;
typedef bf16t bf16x4 __attribute__((ext_vector_type(4)));
typedef bf16t bf16x8 __attribute__((ext_vector_type(8)));
typedef float f32x2 __attribute__((ext_vector_type(2)));
typedef float f32x4 __attribute__((ext_vector_type(4)));
typedef float f32x16 __attribute__((ext_vector_type(16)));
typedef unsigned short u16x8 __attribute__((ext_vector_type(8)));
typedef unsigned int u32x4 __attribute__((ext_vector_type(4)));

#define NB 2
#define NQ 2048
#define NK 2048
#define NH 16
#define ND 64
#define HD (NH * ND) /* 1024 */
#define KVBLK 64
#define NUNITS 512  /* B * H * (Q/128) */
// (1/sqrt(64)) * log2(e): fold scale + base-2 conversion into Q.
#define SCALE_LOG2E 0.18033688011112042f
#define RESCALE_THR 8.0f

// ws layout (per NSPLIT): o_part bf16 [NUNITS*NSPLIT][128][64] then
// ml f32x2 [NUNITS*NSPLIT][128].
#define OPART_BYTES(n) ((size_t)(n) * 8388608ULL)
#define ML_BYTES(n)    ((size_t)(n) * 524288ULL)

// Flash-decode: per (b,h,qt) unit, NSPLIT independent 256-thread blocks each
// process a contiguous KV range (R4 body: 4 q-waves x 32 q, 32x32x16 swapped
// QK^T, in-register softmax via cvt_pk+permlane32_swap, defer-max, LDS 32KB
// double-buffered XOR-swizzled K/V^T). Partials (bf16 o, f32 m,l) go to d_ws;
// a second kernel merges. NSPLIT chosen at launch from ws_size (1 = direct).
__device__ inline unsigned cvt_pk_bf16(float a, float b) {
    unsigned r;
    asm("v_cvt_pk_bf16_f32 %0, %1, %2" : "=v"(r) : "v"(a), "v"(b));
    return r;  // lo16 = bf16(a), hi16 = bf16(b)
}

__device__ inline void plswap(unsigned& a, unsigned& b) {
#if __has_builtin(__builtin_amdgcn_permlane32_swap)
    auto r = __builtin_amdgcn_permlane32_swap(a, b, false, false);
    a = r[0]; b = r[1];
#else
    const unsigned as = __shfl_xor((int)a, 32);
    const unsigned bs = __shfl_xor((int)b, 32);
    const bool lh = (threadIdx.x & 32) != 0;
    const unsigned na = lh ? bs : a;
    const unsigned nb = lh ? b : as;
    a = na; b = nb;
#endif
}

template <int NSPLIT>
__global__ __launch_bounds__(256)
void scan_attn(const float* __restrict__ qs, const float* __restrict__ ks,
               const float* __restrict__ vs, const int* __restrict__ vlen,
               float* __restrict__ out, char* __restrict__ ws)
{
    const int bid = blockIdx.x;
    // XCD = bid&7; alternate batches along each XCD's queue; bijection over
    // (b, h, qt, s) with s varying fastest (spreads splits across XCDs).
    const int x    = bid & 7;
    const int jj   = bid >> 3;
    const int b    = jj & 1;
    const int code = x | ((jj >> 1) << 3);       // [0, 256*NSPLIT)
    const int qt   = code / (16 * NSPLIT);
    const int rr   = code % (16 * NSPLIT);
    const int h    = rr / NSPLIT;
    const int s    = rr % NSPLIT;
    const int uidx = ((b * NH + h) << 4) + qt;

    const int tid  = threadIdx.x;
    const int wq   = tid >> 6;          // q-wave 0..3
    const int lane = tid & 63;
    const int ql   = lane & 31;
    const int lh   = lane >> 5;         // lane half
    const int swq  = (ql & 7) << 4;     // row-XOR swizzle for fragment reads
    const int q    = qt * 128 + wq * 32 + ql;

    const int nkv    = vlen[b];                    // in [1, NK]
    const int ntiles = (nkv + KVBLK - 1) >> 6;
    const int rem    = nkv & 63;                   // 0 -> last tile is full
    const int tlo    = (ntiles * s) / NSPLIT;
    const int thi    = (ntiles * (s + 1)) / NSPLIT;

    const float* qptr = qs + ((size_t)b * NQ + q) * HD + h * ND;
    const float* kptr = ks + (size_t)b * NK * HD + h * ND;
    const float* vptr = vs + (size_t)b * NK * HD + h * ND;

    // double-buffered [ K tile 8KB | V^T tile 8KB ] = 32 KB
    __shared__ __align__(16) char smem[2][16384];

    // ---- Q fragments (B-operand), scale folded in. qf[c]: d = 16c + 8*lh + j
    bf16x8 qf[4];
#pragma unroll
    for (int c = 0; c < 4; ++c) {
        const float* p = qptr + 16 * c + 8 * lh;
        f32x4 lo4 = *reinterpret_cast<const f32x4*>(p);
        f32x4 hi4 = *reinterpret_cast<const f32x4*>(p + 4);
#pragma unroll
        for (int e = 0; e < 4; ++e) {
            qf[c][e]     = (bf16t)(lo4[e] * SCALE_LOG2E);
            qf[c][4 + e] = (bf16t)(hi4[e] * SCALE_LOG2E);
        }
    }

    // ---- staging assignment (256 threads stage 64x64 K and 64x64 V^T)
    const int skr  = tid >> 2;            // K: k-row 0..63
    const int skc2 = (tid & 3) << 5;      // K: 32-byte chunk
    const int ksw  = (skr & 7) << 4;
    const int svd  = tid & 63;            // V: d column (coalesced)
    const int svk2 = (tid >> 6) << 5;     // V: 16 k-rows -> 32 bytes
    const int vsw  = (svd & 7) << 4;

    f32x4 kreg[4];
    float vreg[16];

    auto load_tile = [&](int kb) {
        const float* kp = kptr + (size_t)(kb + skr) * HD + ((tid & 3) << 4);
#pragma unroll
        for (int i = 0; i < 4; ++i)
            kreg[i] = *reinterpret_cast<const f32x4*>(kp + 4 * i);
        const float* vp = vptr + (size_t)(kb + ((tid >> 6) << 4)) * HD + svd;
#pragma unroll
        for (int e = 0; e < 16; ++e)
            vreg[e] = vp[(size_t)e * HD];
    };

    auto store_tile = [&](int buf) {
        u16x8 w0, w1;
#pragma unroll
        for (int i = 0; i < 4; ++i)
#pragma unroll
            for (int e = 0; e < 4; ++e) {
                const int el = 4 * i + e;
                const unsigned short u =
                    __builtin_bit_cast(unsigned short, (bf16t)kreg[i][e]);
                if (el < 8) w0[el] = u; else w1[el - 8] = u;
            }
        char* kb_ = smem[buf] + skr * 128;
        *reinterpret_cast<u16x8*>(kb_ + (skc2 ^ ksw))        = w0;
        *reinterpret_cast<u16x8*>(kb_ + ((skc2 + 16) ^ ksw)) = w1;

        u16x8 x0, x1;
#pragma unroll
        for (int e = 0; e < 16; ++e) {
            const unsigned short u =
                __builtin_bit_cast(unsigned short, (bf16t)vreg[e]);
            if (e < 8) x0[e] = u; else x1[e - 8] = u;
        }
        char* vb_ = smem[buf] + 8192 + svd * 128;
        *reinterpret_cast<u16x8*>(vb_ + (svk2 ^ vsw))        = x0;
        *reinterpret_cast<u16x8*>(vb_ + ((svk2 + 16) ^ vsw)) = x1;
    };

    float mrun = -__builtin_inff();
    float lrun = 0.0f;
    f32x16 o[2] = {};

    if (tlo < thi) { load_tile(tlo << 6); store_tile(0); }
    __syncthreads();

    int cur = 0;
    for (int t = tlo; t < thi; ++t) {
        const int kb = t << 6;
        const bool has_next = (t + 1) < thi;
        if (has_next) load_tile((t + 1) << 6);   // issue early; hide latency

        // ---- S^T = K_tile . Q^T (log2 domain). s_[h2][r]: q=ql,
        //      k = kb + 32*h2 + (r&3) + 8*(r>>2) + 4*lh
        const char* kbuf = smem[cur];
        f32x16 s_[2];
#pragma unroll
        for (int h2 = 0; h2 < 2; ++h2) {
            f32x16 acc = {};
            const char* krow = kbuf + (32 * h2 + ql) * 128;
#pragma unroll
            for (int c = 0; c < 4; ++c) {
                bf16x8 kf = *reinterpret_cast<const bf16x8*>(
                    krow + ((32 * c + 16 * lh) ^ swq));
                acc = __builtin_amdgcn_mfma_f32_32x32x16_bf16(kf, qf[c], acc, 0, 0, 0);
            }
            s_[h2] = acc;
        }

        // ---- tail mask (only the block owning the globally-last tile)
        if (rem && t == ntiles - 1) {
            const int krem = nkv - kb;
#pragma unroll
            for (int h2 = 0; h2 < 2; ++h2)
#pragma unroll
                for (int r = 0; r < 16; ++r)
                    if (32 * h2 + (r & 3) + 8 * (r >> 2) + 4 * lh >= krem)
                        s_[h2][r] = -__builtin_inff();
        }

        // ---- online softmax (row = lanes l and l^32)
        float pmax = -__builtin_inff();
#pragma unroll
        for (int h2 = 0; h2 < 2; ++h2)
#pragma unroll
            for (int r = 0; r < 16; ++r) pmax = fmaxf(pmax, s_[h2][r]);
        pmax = fmaxf(pmax, __shfl_xor(pmax, 32));

        if (!__all(pmax <= mrun + RESCALE_THR)) {   // defer-max (T13)
            const float mnew  = fmaxf(mrun, pmax);
            const float alpha = exp2f(mrun - mnew);
            lrun *= alpha;
            o[0] *= alpha;
            o[1] *= alpha;
            mrun = mnew;
        }

        float ps = 0.0f;
#pragma unroll
        for (int h2 = 0; h2 < 2; ++h2)
#pragma unroll
            for (int r = 0; r < 16; ++r) {
                const float pv = exp2f(s_[h2][r] - mrun);
                s_[h2][r] = pv;
                ps += pv;
            }
        ps += __shfl_xor(ps, 32);
        lrun += ps;

        // ---- P -> PV B-fragments in-register (T12)
        bf16x8 pf[4];
#pragma unroll
        for (int c = 0; c < 4; ++c) {
            const int h2 = c >> 1, r0 = (c & 1) * 8;
            unsigned a0 = cvt_pk_bf16(s_[h2][r0 + 0], s_[h2][r0 + 1]);
            unsigned b0 = cvt_pk_bf16(s_[h2][r0 + 4], s_[h2][r0 + 5]);
            plswap(a0, b0);
            unsigned a1 = cvt_pk_bf16(s_[h2][r0 + 2], s_[h2][r0 + 3]);
            unsigned b1 = cvt_pk_bf16(s_[h2][r0 + 6], s_[h2][r0 + 7]);
            plswap(a1, b1);
            pf[c] = __builtin_bit_cast(bf16x8, (u32x4){a0, a1, b0, b1});
        }

        // ---- O^T += V^T . P^T
        const char* vbuf = smem[cur] + 8192;
#pragma unroll
        for (int dt = 0; dt < 2; ++dt) {
            const char* vrow = vbuf + (32 * dt + ql) * 128;
#pragma unroll
            for (int c = 0; c < 4; ++c) {
                bf16x8 vf = *reinterpret_cast<const bf16x8*>(
                    vrow + ((32 * c + 16 * lh) ^ swq));
                o[dt] = __builtin_amdgcn_mfma_f32_32x32x16_bf16(vf, pf[c], o[dt], 0, 0, 0);
            }
        }

        if (has_next) store_tile(cur ^ 1);
        __syncthreads();
        cur ^= 1;
    }

    if (NSPLIT == 1) {
        // ---- direct: normalize + store
        const float inv = 1.0f / lrun;
        float* op = out + ((size_t)b * NQ + q) * HD + h * ND;
#pragma unroll
        for (int dt = 0; dt < 2; ++dt)
#pragma unroll
            for (int rg = 0; rg < 4; ++rg) {
                f32x4 w;
#pragma unroll
                for (int e = 0; e < 4; ++e) w[e] = o[dt][4 * rg + e] * inv;
                *reinterpret_cast<f32x4*>(op + 32 * dt + 8 * rg + 4 * lh) = w;
            }
    } else {
        // ---- partial: bf16 o + f32 (m,l) to ws
        const int p = uidx * NSPLIT + s;
        bf16t* op = (bf16t*)ws + ((size_t)p * 128 + wq * 32 + ql) * 64;
#pragma unroll
        for (int dt = 0; dt < 2; ++dt)
#pragma unroll
            for (int rg = 0; rg < 4; ++rg) {
                bf16x4 w;
#pragma unroll
                for (int e = 0; e < 4; ++e) w[e] = (bf16t)o[dt][4 * rg + e];
                *reinterpret_cast<bf16x4*>(op + 32 * dt + 8 * rg + 4 * lh) = w;
            }
        if (lh == 0) {
            f32x2* ml = (f32x2*)(ws + OPART_BYTES(NSPLIT));
            ml[p * 128 + wq * 32 + ql] = (f32x2){mrun, lrun};
        }
    }
}

template <int NSPLIT>
__global__ __launch_bounds__(256)
void merge_attn(const char* __restrict__ ws, float* __restrict__ out)
{
    const int u  = blockIdx.x;          // (b*16+h)*16+qt
    const int b  = u >> 8;
    const int h  = (u >> 4) & 15;
    const int qt = u & 15;
    const int tid = threadIdx.x;
    const int q  = tid >> 1;            // 0..127
    const int dh = (tid & 1) * 32;      // d base

    const bf16t* opart = (const bf16t*)ws;
    const f32x2* ml    = (const f32x2*)(ws + OPART_BYTES(NSPLIT));

    float m_s[NSPLIT], l_s[NSPLIT];
    float M = -__builtin_inff();
#pragma unroll
    for (int s = 0; s < NSPLIT; ++s) {
        f32x2 v = ml[(u * NSPLIT + s) * 128 + q];
        m_s[s] = v[0]; l_s[s] = v[1];
        M = fmaxf(M, v[0]);
    }
    float L = 0.0f, w_s[NSPLIT];
#pragma unroll
    for (int s = 0; s < NSPLIT; ++s) {
        w_s[s] = exp2f(m_s[s] - M);     // 0 for empty splits (m=-inf)
        L += w_s[s] * l_s[s];
    }
    const float inv = 1.0f / L;

    float acc[32];
#pragma unroll
    for (int e = 0; e < 32; ++e) acc[e] = 0.0f;
#pragma unroll
    for (int s = 0; s < NSPLIT; ++s) {
        const bf16t* op = opart + ((size_t)(u * NSPLIT + s) * 128 + q) * 64 + dh;
#pragma unroll
        for (int c = 0; c < 4; ++c) {
            bf16x8 v8 = *reinterpret_cast<const bf16x8*>(op + 8 * c);
#pragma unroll
            for (int e = 0; e < 8; ++e)
                acc[8 * c + e] += w_s[s] * (float)v8[e];
        }
    }

    float* op = out + ((size_t)b * NQ + qt * 128 + q) * HD + h * ND + dh;
#pragma unroll
    for (int c = 0; c < 8; ++c) {
        f32x4 st;
#pragma unroll
        for (int e = 0; e < 4; ++e) st[e] = acc[4 * c + e] * inv;
        *reinterpret_cast<f32x4*>(op + 4 * c) = st;
    }
}

extern "C" void kernel_launch(void* const* d_in, const int* in_sizes, int n_in,
                              void* d_out, int out_size, void* d_ws, size_t ws_size,
                              hipStream_t stream)
{
    const float* qs   = (const float*)d_in[0];
    const float* ks   = (const float*)d_in[1];
    const float* vs   = (const float*)d_in[2];
    const int*   vlen = (const int*)d_in[3];
    float* out = (float*)d_out;
    char*  ws  = (char*)d_ws;

    const size_t need4 = OPART_BYTES(4) + ML_BYTES(4);   // ~35.7 MB
    const size_t need2 = OPART_BYTES(2) + ML_BYTES(2);   // ~17.8 MB

    if (ws_size >= need4) {
        scan_attn<4><<<NUNITS * 4, 256, 0, stream>>>(qs, ks, vs, vlen, out, ws);
        merge_attn<4><<<NUNITS, 256, 0, stream>>>(ws, out);
    } else if (ws_size >= need2) {
        scan_attn<2><<<NUNITS * 2, 256, 0, stream>>>(qs, ks, vs, vlen, out, ws);
        merge_attn<2><<<NUNITS, 256, 0, stream>>>(ws, out);
    } else {
        scan_attn<1><<<NUNITS, 256, 0, stream>>>(qs, ks, vs, vlen, out, ws);
    }
}

// Round 9
// 65.624 us; speedup vs baseline: 1.3042x; 1.3042x over previous
//
#include <hip/hip_runtime.h>
#include <hip/hip_bf16.h>

typedef __bf16 bf16t;
typedef bf16t bf16x4 __attribute__((ext_vector_type(4)));
typedef bf16t bf16x8 __attribute__((ext_vector_type(8)));
typedef float f32x2 __attribute__((ext_vector_type(2)));
typedef float f32x4 __attribute__((ext_vector_type(4)));
typedef float f32x16 __attribute__((ext_vector_type(16)));
typedef unsigned short u16x8 __attribute__((ext_vector_type(8)));
typedef unsigned int u32x4 __attribute__((ext_vector_type(4)));

#define NB 2
#define NQ 2048
#define NK 2048
#define NH 16
#define ND 64
#define HD (NH * ND) /* 1024 */
#define KVBLK 64
#define NUNITS 512  /* B * H * (Q/128) */
// (1/sqrt(64)) * log2(e): fold scale + base-2 conversion into Q.
#define SCALE_LOG2E 0.18033688011112042f
#define RESCALE_THR 8.0f

// ws layout (per NSPLIT): o_part bf16 [NUNITS*NSPLIT][128][64] then
// ml f32x2 [NUNITS*NSPLIT][128].
#define OPART_BYTES(n) ((size_t)(n) * 8388608ULL)
#define ML_BYTES(n)    ((size_t)(n) * 524288ULL)

// R9: register-diet + forced occupancy. Evidence R4/R7/R8: dur pinned ~62us
// across structures; VGPR_Count (arch-only) 120 + ~64 AGPR (s_, o accums)
// ≈ 184/wave -> 2 waves/SIMD cap. Fix: __launch_bounds__(256,3) (blocks/CU
// semantics, verified R5-R7) caps total at 170; staging split into two
// staggered halves (kreg/vreg 32->16 regs) to fit. Split-2 over KV (1024
// blocks) so 3 blocks/CU has work; bf16 partials merged by a second kernel.
__device__ inline unsigned cvt_pk_bf16(float a, float b) {
    unsigned r;
    asm("v_cvt_pk_bf16_f32 %0, %1, %2" : "=v"(r) : "v"(a), "v"(b));
    return r;  // lo16 = bf16(a), hi16 = bf16(b)
}

__device__ inline void plswap(unsigned& a, unsigned& b) {
#if __has_builtin(__builtin_amdgcn_permlane32_swap)
    auto r = __builtin_amdgcn_permlane32_swap(a, b, false, false);
    a = r[0]; b = r[1];
#else
    const unsigned as = __shfl_xor((int)a, 32);
    const unsigned bs = __shfl_xor((int)b, 32);
    const bool lh = (threadIdx.x & 32) != 0;
    const unsigned na = lh ? bs : a;
    const unsigned nb = lh ? b : as;
    a = na; b = nb;
#endif
}

template <int NSPLIT>
__global__ __launch_bounds__(256, 3)
void scan_attn(const float* __restrict__ qs, const float* __restrict__ ks,
               const float* __restrict__ vs, const int* __restrict__ vlen,
               float* __restrict__ out, char* __restrict__ ws)
{
    const int bid = blockIdx.x;
    // XCD = bid&7; alternate batches along each XCD's queue; bijection over
    // (b, h, qt, s) with s varying fastest.
    const int x    = bid & 7;
    const int jj   = bid >> 3;
    const int b    = jj & 1;
    const int code = x | ((jj >> 1) << 3);       // [0, 256*NSPLIT)
    const int qt   = code / (16 * NSPLIT);
    const int rr   = code % (16 * NSPLIT);
    const int h    = rr / NSPLIT;
    const int s    = rr % NSPLIT;
    const int uidx = ((b * NH + h) << 4) + qt;

    const int tid  = threadIdx.x;
    const int wq   = tid >> 6;          // q-wave 0..3
    const int lane = tid & 63;
    const int ql   = lane & 31;
    const int lh   = lane >> 5;         // lane half
    const int swq  = (ql & 7) << 4;     // row-XOR swizzle for fragment reads
    const int q    = qt * 128 + wq * 32 + ql;

    const int nkv    = vlen[b];                    // in [1, NK]
    const int ntiles = (nkv + KVBLK - 1) >> 6;
    const int rem    = nkv & 63;                   // 0 -> last tile is full
    const int tlo    = (ntiles * s) / NSPLIT;
    const int thi    = (ntiles * (s + 1)) / NSPLIT;

    const float* qptr = qs + ((size_t)b * NQ + q) * HD + h * ND;
    const float* kptr = ks + (size_t)b * NK * HD + h * ND;
    const float* vptr = vs + (size_t)b * NK * HD + h * ND;

    // double-buffered [ K tile 8KB | V^T tile 8KB ] = 32 KB
    __shared__ __align__(16) char smem[2][16384];

    // ---- Q fragments (B-operand), scale folded in. qf[c]: d = 16c + 8*lh + j
    bf16x8 qf[4];
#pragma unroll
    for (int c = 0; c < 4; ++c) {
        const float* p = qptr + 16 * c + 8 * lh;
        f32x4 lo4 = *reinterpret_cast<const f32x4*>(p);
        f32x4 hi4 = *reinterpret_cast<const f32x4*>(p + 4);
#pragma unroll
        for (int e = 0; e < 4; ++e) {
            qf[c][e]     = (bf16t)(lo4[e] * SCALE_LOG2E);
            qf[c][4 + e] = (bf16t)(hi4[e] * SCALE_LOG2E);
        }
    }

    // ---- staggered half staging: 256 threads stage 32 K-rows + 32 V^T-k per half
    const int skr  = tid >> 3;             // K: k-row 0..31 within half
    const int skc  = (tid & 7) << 3;       // K: 8-float chunk
    const int skc2 = (tid & 7) << 4;       // dest bytes
    const int ksw  = (skr & 7) << 4;
    const int svd  = tid & 63;             // V: d column (coalesced global read)
    const int svk8 = (tid >> 6) << 3;      // V: 8 k-rows within half
    const int svk2 = (tid >> 6) << 4;      // dest bytes within half
    const int vsw  = (svd & 7) << 4;

    f32x4 kreg[2];
    float vreg[8];

    auto load_half = [&](int kb, int half) {
        const float* kp = kptr + (size_t)(kb + half * 32 + skr) * HD + skc;
        kreg[0] = *reinterpret_cast<const f32x4*>(kp);
        kreg[1] = *reinterpret_cast<const f32x4*>(kp + 4);
        const float* vp = vptr + (size_t)(kb + half * 32 + svk8) * HD + svd;
#pragma unroll
        for (int e = 0; e < 8; ++e)
            vreg[e] = vp[(size_t)e * HD];
    };

    auto store_half = [&](int buf, int half) {
        u16x8 w0;
#pragma unroll
        for (int i = 0; i < 2; ++i)
#pragma unroll
            for (int e = 0; e < 4; ++e)
                w0[4 * i + e] = __builtin_bit_cast(unsigned short, (bf16t)kreg[i][e]);
        char* kb_ = smem[buf] + (half * 32 + skr) * 128;
        *reinterpret_cast<u16x8*>(kb_ + (skc2 ^ ksw)) = w0;

        u16x8 x0;
#pragma unroll
        for (int e = 0; e < 8; ++e)
            x0[e] = __builtin_bit_cast(unsigned short, (bf16t)vreg[e]);
        char* vb_ = smem[buf] + 8192 + svd * 128;
        *reinterpret_cast<u16x8*>(vb_ + ((svk2 + half * 64) ^ vsw)) = x0;
    };

    float mrun = -__builtin_inff();
    float lrun = 0.0f;
    f32x16 o[2] = {};

    if (tlo < thi) {
        load_half(tlo << 6, 0); store_half(0, 0);
        load_half(tlo << 6, 1); store_half(0, 1);
    }
    __syncthreads();

    int cur = 0;
    for (int t = tlo; t < thi; ++t) {
        const int kb = t << 6;
        const bool has_next = (t + 1) < thi;
        if (has_next) load_half((t + 1) << 6, 0);   // half A in flight over QK

        // ---- S^T = K_tile . Q^T (log2 domain). s_[h2][r]: q=ql,
        //      k = kb + 32*h2 + (r&3) + 8*(r>>2) + 4*lh
        const char* kbuf = smem[cur];
        f32x16 s_[2];
#pragma unroll
        for (int h2 = 0; h2 < 2; ++h2) {
            f32x16 acc = {};
            const char* krow = kbuf + (32 * h2 + ql) * 128;
#pragma unroll
            for (int c = 0; c < 4; ++c) {
                bf16x8 kf = *reinterpret_cast<const bf16x8*>(
                    krow + ((32 * c + 16 * lh) ^ swq));
                acc = __builtin_amdgcn_mfma_f32_32x32x16_bf16(kf, qf[c], acc, 0, 0, 0);
            }
            s_[h2] = acc;
        }

        if (has_next) {
            store_half(cur ^ 1, 0);                 // waits only half-A loads
            load_half((t + 1) << 6, 1);             // half B in flight over PV
        }

        // ---- tail mask (only the block owning the globally-last tile)
        if (rem && t == ntiles - 1) {
            const int krem = nkv - kb;
#pragma unroll
            for (int h2 = 0; h2 < 2; ++h2)
#pragma unroll
                for (int r = 0; r < 16; ++r)
                    if (32 * h2 + (r & 3) + 8 * (r >> 2) + 4 * lh >= krem)
                        s_[h2][r] = -__builtin_inff();
        }

        // ---- online softmax (row = lanes l and l^32)
        float pmax = -__builtin_inff();
#pragma unroll
        for (int h2 = 0; h2 < 2; ++h2)
#pragma unroll
            for (int r = 0; r < 16; ++r) pmax = fmaxf(pmax, s_[h2][r]);
        pmax = fmaxf(pmax, __shfl_xor(pmax, 32));

        if (!__all(pmax <= mrun + RESCALE_THR)) {   // defer-max (T13)
            const float mnew  = fmaxf(mrun, pmax);
            const float alpha = exp2f(mrun - mnew);
            lrun *= alpha;
            o[0] *= alpha;
            o[1] *= alpha;
            mrun = mnew;
        }

        float ps = 0.0f;
#pragma unroll
        for (int h2 = 0; h2 < 2; ++h2)
#pragma unroll
            for (int r = 0; r < 16; ++r) {
                const float pv = exp2f(s_[h2][r] - mrun);
                s_[h2][r] = pv;
                ps += pv;
            }
        ps += __shfl_xor(ps, 32);
        lrun += ps;

        // ---- P -> PV B-fragments in-register (T12)
        bf16x8 pf[4];
#pragma unroll
        for (int c = 0; c < 4; ++c) {
            const int h2 = c >> 1, r0 = (c & 1) * 8;
            unsigned a0 = cvt_pk_bf16(s_[h2][r0 + 0], s_[h2][r0 + 1]);
            unsigned b0 = cvt_pk_bf16(s_[h2][r0 + 4], s_[h2][r0 + 5]);
            plswap(a0, b0);
            unsigned a1 = cvt_pk_bf16(s_[h2][r0 + 2], s_[h2][r0 + 3]);
            unsigned b1 = cvt_pk_bf16(s_[h2][r0 + 6], s_[h2][r0 + 7]);
            plswap(a1, b1);
            pf[c] = __builtin_bit_cast(bf16x8, (u32x4){a0, a1, b0, b1});
        }

        // ---- O^T += V^T . P^T
        const char* vbuf = smem[cur] + 8192;
#pragma unroll
        for (int dt = 0; dt < 2; ++dt) {
            const char* vrow = vbuf + (32 * dt + ql) * 128;
#pragma unroll
            for (int c = 0; c < 4; ++c) {
                bf16x8 vf = *reinterpret_cast<const bf16x8*>(
                    vrow + ((32 * c + 16 * lh) ^ swq));
                o[dt] = __builtin_amdgcn_mfma_f32_32x32x16_bf16(vf, pf[c], o[dt], 0, 0, 0);
            }
        }

        if (has_next) store_half(cur ^ 1, 1);       // waits only half-B loads
        __syncthreads();
        cur ^= 1;
    }

    if (NSPLIT == 1) {
        // ---- direct: normalize + store
        const float inv = 1.0f / lrun;
        float* op = out + ((size_t)b * NQ + q) * HD + h * ND;
#pragma unroll
        for (int dt = 0; dt < 2; ++dt)
#pragma unroll
            for (int rg = 0; rg < 4; ++rg) {
                f32x4 w;
#pragma unroll
                for (int e = 0; e < 4; ++e) w[e] = o[dt][4 * rg + e] * inv;
                *reinterpret_cast<f32x4*>(op + 32 * dt + 8 * rg + 4 * lh) = w;
            }
    } else {
        // ---- partial: bf16 o + f32 (m,l) to ws
        const int p = uidx * NSPLIT + s;
        bf16t* op = (bf16t*)ws + ((size_t)p * 128 + wq * 32 + ql) * 64;
#pragma unroll
        for (int dt = 0; dt < 2; ++dt)
#pragma unroll
            for (int rg = 0; rg < 4; ++rg) {
                bf16x4 w;
#pragma unroll
                for (int e = 0; e < 4; ++e) w[e] = (bf16t)o[dt][4 * rg + e];
                *reinterpret_cast<bf16x4*>(op + 32 * dt + 8 * rg + 4 * lh) = w;
            }
        if (lh == 0) {
            f32x2* ml = (f32x2*)(ws + OPART_BYTES(NSPLIT));
            ml[p * 128 + wq * 32 + ql] = (f32x2){mrun, lrun};
        }
    }
}

template <int NSPLIT>
__global__ __launch_bounds__(256)
void merge_attn(const char* __restrict__ ws, float* __restrict__ out)
{
    const int u  = blockIdx.x;          // (b*16+h)*16+qt
    const int b  = u >> 8;
    const int h  = (u >> 4) & 15;
    const int qt = u & 15;
    const int tid = threadIdx.x;
    const int q  = tid >> 1;            // 0..127
    const int dh = (tid & 1) * 32;      // d base

    const bf16t* opart = (const bf16t*)ws;
    const f32x2* ml    = (const f32x2*)(ws + OPART_BYTES(NSPLIT));

    float m_s[NSPLIT], l_s[NSPLIT];
    float M = -__builtin_inff();
#pragma unroll
    for (int s = 0; s < NSPLIT; ++s) {
        f32x2 v = ml[(u * NSPLIT + s) * 128 + q];
        m_s[s] = v[0]; l_s[s] = v[1];
        M = fmaxf(M, v[0]);
    }
    float L = 0.0f, w_s[NSPLIT];
#pragma unroll
    for (int s = 0; s < NSPLIT; ++s) {
        w_s[s] = exp2f(m_s[s] - M);     // 0 for empty splits (m=-inf)
        L += w_s[s] * l_s[s];
    }
    const float inv = 1.0f / L;

    float acc[32];
#pragma unroll
    for (int e = 0; e < 32; ++e) acc[e] = 0.0f;
#pragma unroll
    for (int s = 0; s < NSPLIT; ++s) {
        const bf16t* op = opart + ((size_t)(u * NSPLIT + s) * 128 + q) * 64 + dh;
#pragma unroll
        for (int c = 0; c < 4; ++c) {
            bf16x8 v8 = *reinterpret_cast<const bf16x8*>(op + 8 * c);
#pragma unroll
            for (int e = 0; e < 8; ++e)
                acc[8 * c + e] += w_s[s] * (float)v8[e];
        }
    }

    float* op = out + ((size_t)b * NQ + qt * 128 + q) * HD + h * ND + dh;
#pragma unroll
    for (int c = 0; c < 8; ++c) {
        f32x4 st;
#pragma unroll
        for (int e = 0; e < 4; ++e) st[e] = acc[4 * c + e] * inv;
        *reinterpret_cast<f32x4*>(op + 4 * c) = st;
    }
}

extern "C" void kernel_launch(void* const* d_in, const int* in_sizes, int n_in,
                              void* d_out, int out_size, void* d_ws, size_t ws_size,
                              hipStream_t stream)
{
    const float* qs   = (const float*)d_in[0];
    const float* ks   = (const float*)d_in[1];
    const float* vs   = (const float*)d_in[2];
    const int*   vlen = (const int*)d_in[3];
    float* out = (float*)d_out;
    char*  ws  = (char*)d_ws;

    const size_t need2 = OPART_BYTES(2) + ML_BYTES(2);   // ~17.8 MB

    if (ws_size >= need2) {
        scan_attn<2><<<NUNITS * 2, 256, 0, stream>>>(qs, ks, vs, vlen, out, ws);
        merge_attn<2><<<NUNITS, 256, 0, stream>>>(ws, out);
    } else {
        scan_attn<1><<<NUNITS, 256, 0, stream>>>(qs, ks, vs, vlen, out, ws);
    }
}